// Round 1
// baseline (178.699 us; speedup 1.0000x reference)
//
#include <hip/hip_runtime.h>
#include <hip/hip_bf16.h>

typedef __attribute__((ext_vector_type(8))) short bf16x8;
typedef __attribute__((ext_vector_type(4))) float f32x4;

#define LRELU_ALPHA 0.2f

__device__ __forceinline__ unsigned short f2bf(float x) {
    unsigned u = __float_as_uint(x);
    u += 0x7fffu + ((u >> 16) & 1u);   // RNE; inputs are finite
    return (unsigned short)(u >> 16);
}

// ---------------- Stage 1: Wh = x @ W^T + bW  (fp32) ----------------
// x: [12800][256], W: [256][256] (row f, k inner) -> Wh [12800][256]
// BM=128, BN=128, BK=32; 256 threads; grid (100, 2)
__global__ __launch_bounds__(256) void k_gemm_wh(
    const float* __restrict__ x, const float* __restrict__ W,
    const float* __restrict__ bW, float* __restrict__ Wh)
{
    __shared__ alignas(16) float As[32][132];  // [kk][row], pad 132 for write conflicts, 16B-aligned rows
    __shared__ alignas(16) float Bs[32][132];  // [kk][f]
    const int t  = threadIdx.x;
    const int r0 = blockIdx.x * 128;
    const int f0 = blockIdx.y * 128;
    const int tx = t & 15, ty = t >> 4;
    const int li = t >> 3;          // 0..31
    const int lk = (t & 7) << 2;    // 0,4,..,28

    float acc[8][8];
#pragma unroll
    for (int i = 0; i < 8; ++i)
#pragma unroll
        for (int j = 0; j < 8; ++j) acc[i][j] = 0.f;

    for (int k0 = 0; k0 < 256; k0 += 32) {
        float4 av[4], bv[4];
#pragma unroll
        for (int q = 0; q < 4; ++q) {
            av[q] = *(const float4*)&x[(size_t)(r0 + li + 32*q)*256 + k0 + lk];
            bv[q] = *(const float4*)&W[(size_t)(f0 + li + 32*q)*256 + k0 + lk];
        }
        __syncthreads();   // prev compute done before overwrite
#pragma unroll
        for (int q = 0; q < 4; ++q) {
            const float* a = (const float*)&av[q];
            const float* b = (const float*)&bv[q];
#pragma unroll
            for (int e = 0; e < 4; ++e) {
                As[lk + e][li + 32*q] = a[e];
                Bs[lk + e][li + 32*q] = b[e];
            }
        }
        __syncthreads();
#pragma unroll
        for (int kk = 0; kk < 32; ++kk) {
            float a[8], b[8];
            *(float4*)&a[0] = *(const float4*)&As[kk][4*tx ? 4*ty : 4*ty]; // (see below, kept simple)
            *(float4*)&a[0] = *(const float4*)&As[kk][4*ty];
            *(float4*)&a[4] = *(const float4*)&As[kk][64 + 4*ty];
            *(float4*)&b[0] = *(const float4*)&Bs[kk][4*tx];
            *(float4*)&b[4] = *(const float4*)&Bs[kk][64 + 4*tx];
#pragma unroll
            for (int i = 0; i < 8; ++i)
#pragma unroll
                for (int j = 0; j < 8; ++j)
                    acc[i][j] = __builtin_fmaf(a[i], b[j], acc[i][j]);
        }
    }
    float4 bw0 = *(const float4*)&bW[f0 + 4*tx];
    float4 bw1 = *(const float4*)&bW[f0 + 64 + 4*tx];
#pragma unroll
    for (int ah = 0; ah < 2; ++ah)
#pragma unroll
        for (int e = 0; e < 4; ++e) {
            int r = r0 + ah*64 + 4*ty + e;
            float4 v0, v1;
            v0.x = acc[ah*4+e][0] + bw0.x; v0.y = acc[ah*4+e][1] + bw0.y;
            v0.z = acc[ah*4+e][2] + bw0.z; v0.w = acc[ah*4+e][3] + bw0.w;
            v1.x = acc[ah*4+e][4] + bw1.x; v1.y = acc[ah*4+e][5] + bw1.y;
            v1.z = acc[ah*4+e][6] + bw1.z; v1.w = acc[ah*4+e][7] + bw1.w;
            *(float4*)&Wh[(size_t)r*256 + f0 + 4*tx] = v0;
            *(float4*)&Wh[(size_t)r*256 + f0 + 64 + 4*tx] = v1;
        }
}

// ---------------- Stage 2: Wh1/Wh2 row dots (fp32) ----------------
__global__ __launch_bounds__(256) void k_rowdots(
    const float* __restrict__ Wh, const float* __restrict__ ai,
    const float* __restrict__ bi, const float* __restrict__ aj,
    const float* __restrict__ bj,
    float* __restrict__ Wh1, float* __restrict__ Wh2)
{
    const int lane = threadIdx.x & 63;
    const int r = blockIdx.x * 4 + (threadIdx.x >> 6);
    float4 w4 = *(const float4*)&Wh[(size_t)r*256 + lane*4];
    float4 a4 = *(const float4*)&ai[lane*4];
    float4 c4 = *(const float4*)&aj[lane*4];
    float s1 = w4.x*a4.x + w4.y*a4.y + w4.z*a4.z + w4.w*a4.w;
    float s2 = w4.x*c4.x + w4.y*c4.y + w4.z*c4.z + w4.w*c4.w;
#pragma unroll
    for (int m = 1; m < 64; m <<= 1) {
        s1 += __shfl_xor(s1, m, 64);
        s2 += __shfl_xor(s2, m, 64);
    }
    if (lane == 0) {
        Wh1[r] = s1 + bi[0];
        Wh2[r] = s2 + bj[0];
    }
}

// ---------------- Stage 3: WhT[b][f][n] = bf16(Wh[b][n][f]) ----------------
// grid (25, 4, 8) = (n-tile64, f-tile64, b); 256 threads
__global__ __launch_bounds__(256) void k_transpose(
    const float* __restrict__ Wh, unsigned short* __restrict__ WhT)
{
    __shared__ alignas(16) unsigned short tile[64][72];  // [f][n], pad to 72 (rows 144B, 16B-aligned)
    const int t = threadIdx.x;
    const int n0 = blockIdx.x * 64, f0 = blockIdx.y * 64, b = blockIdx.z;
    const int fi = (t & 15) * 4;
    const int i0 = t >> 4;
#pragma unroll
    for (int q = 0; q < 4; ++q) {
        int i = i0 + 16*q;
        float4 v = *(const float4*)&Wh[(size_t)(b*1600 + n0 + i)*256 + f0 + fi];
        tile[fi+0][i] = f2bf(v.x);
        tile[fi+1][i] = f2bf(v.y);
        tile[fi+2][i] = f2bf(v.z);
        tile[fi+3][i] = f2bf(v.w);
    }
    __syncthreads();
    const int f = t >> 2;
    const int nq = t & 3;
    int4 u0 = *(const int4*)&tile[f][nq*16];
    int4 u1 = *(const int4*)&tile[f][nq*16 + 8];
    size_t o = (size_t)(b*256 + f0 + f)*1600 + n0 + nq*16;
    *(int4*)&WhT[o] = u0;
    *(int4*)&WhT[o + 8] = u1;
}

// ---------------- Stage 4: fused flash attention + ELU ----------------
// grid (50, 8) = (i-tile32, b); 256 threads (4 waves)
// whs: [f][jj] bf16, 256x64, linear store via global_load_lds with
//      inverse-swizzled global source; reads XOR-swizzle byte ^((f&7)<<4).
// pls: [i][jj] bf16, 32x64, swizzled writes+reads ^((i&7)<<4).
__global__ __launch_bounds__(256) void k_attn(
    const unsigned short* __restrict__ WhT,   // [8][256][1600] bf16
    const float* __restrict__ Wh1, const float* __restrict__ Wh2,
    const int* __restrict__ adj, float* __restrict__ out)
{
    __shared__ alignas(16) unsigned short whs[256*64];
    __shared__ alignas(16) unsigned short pls[32*64];
    __shared__ float scale_s[32];
    __shared__ float l_s[32];

    const int t = threadIdx.x;
    const int w = t >> 6;
    const int l = t & 63;
    const int b = blockIdx.y;
    const int i0 = blockIdx.x * 32;

    // score-phase ids: 16 jj-lanes x 4 row-pairs per wave
    const int jj16 = l & 15;
    const int rr = (l >> 4) & 3;
    const int row0 = w*8 + rr*2;
    float wh1v[2];
    wh1v[0] = Wh1[b*1600 + i0 + row0 + 0];
    wh1v[1] = Wh1[b*1600 + i0 + row0 + 1];
    float m_r[2] = {-INFINITY, -INFINITY};
    float l_r[2] = {0.f, 0.f};

    // PV ids
    const int cl = l & 15;
    const int kg = l >> 4;
    f32x4 acc[2][4];
#pragma unroll
    for (int a = 0; a < 2; ++a)
#pragma unroll
        for (int c = 0; c < 4; ++c) acc[a][c] = (f32x4){0.f, 0.f, 0.f, 0.f};

    const unsigned short* whtb = WhT + (size_t)b * 256 * 1600;
    const int sfr = w*8 + (l >> 3);   // staging f-row within 32-row group
    const int sc_ = l & 7;            // staging 16B chunk

    for (int jt = 0; jt < 25; ++jt) {
        const int j0 = jt * 64;
        // --- stage whs tile (async, pre-swizzled source, linear LDS dest) ---
#pragma unroll
        for (int q = 0; q < 8; ++q) {
            int f = q*32 + sfr;
            int cs = sc_ ^ (f & 7);
            const unsigned short* g = whtb + (size_t)f*1600 + j0 + cs*8;
            unsigned short* lp = &whs[(q*32 + w*8) * 64];
            __builtin_amdgcn_global_load_lds(
                (const __attribute__((address_space(1))) unsigned int*)g,
                (__attribute__((address_space(3))) unsigned int*)lp, 16, 0, 0);
        }
        // --- scores + online softmax (fp32, exact vs reference) ---
        float4 wh2 = *(const float4*)&Wh2[b*1600 + j0 + jj16*4];
        const float* w2 = (const float*)&wh2;
#pragma unroll
        for (int r = 0; r < 2; ++r) {
            const int gi = i0 + row0 + r;
            int4 a4 = *(const int4*)&adj[(size_t)gi*1600 + j0 + jj16*4];
            const int* am = (const int*)&a4;
            float s[4];
#pragma unroll
            for (int q = 0; q < 4; ++q) {
                float raw = wh1v[r] + w2[q];
                float lr = raw > 0.f ? raw : LRELU_ALPHA * raw;
                s[q] = (am[q] > 0) ? lr : -1e9f;
            }
            float tmax = fmaxf(fmaxf(s[0], s[1]), fmaxf(s[2], s[3]));
#pragma unroll
            for (int m = 1; m < 16; m <<= 1)
                tmax = fmaxf(tmax, __shfl_xor(tmax, m, 64));
            float mnew = fmaxf(m_r[r], tmax);
            float fac = __expf(m_r[r] - mnew);   // first tile: exp(-inf)=0
            float p0 = __expf(s[0]-mnew), p1 = __expf(s[1]-mnew);
            float p2 = __expf(s[2]-mnew), p3 = __expf(s[3]-mnew);
            float tsum = (p0+p1)+(p2+p3);
#pragma unroll
            for (int m = 1; m < 16; m <<= 1)
                tsum += __shfl_xor(tsum, m, 64);
            l_r[r] = l_r[r]*fac + tsum;
            m_r[r] = mnew;
            // write P (bf16, swizzled)
            const int i = row0 + r;
            ushort4 pk;
            pk.x = f2bf(p0); pk.y = f2bf(p1); pk.z = f2bf(p2); pk.w = f2bf(p3);
            int off = i*128 + jj16*8;
            off ^= (i & 7) << 4;
            *(ushort4*)((char*)pls + off) = pk;
            if (jj16 == 0) {
                scale_s[i] = fac;
                if (jt == 24) l_s[i] = l_r[r];
            }
        }
        asm volatile("s_waitcnt vmcnt(0)" ::: "memory");
        __syncthreads();
        // --- rescale accumulators ---
#pragma unroll
        for (int mi = 0; mi < 2; ++mi)
#pragma unroll
            for (int rg = 0; rg < 4; ++rg) {
                float sc = scale_s[mi*16 + kg*4 + rg];
#pragma unroll
                for (int nf = 0; nf < 4; ++nf) acc[mi][nf][rg] *= sc;
            }
        // --- PV via MFMA: wave w covers f-cols [64w, 64w+64) ---
#pragma unroll
        for (int kb = 0; kb < 2; ++kb) {
            bf16x8 af[2], bfr[4];
#pragma unroll
            for (int mi = 0; mi < 2; ++mi) {
                int i = mi*16 + cl;
                int off = i*128 + kb*64 + kg*16;
                off ^= (i & 7) << 4;
                af[mi] = *(const bf16x8*)((const char*)pls + off);
            }
#pragma unroll
            for (int nf = 0; nf < 4; ++nf) {
                int f = w*64 + nf*16 + cl;
                int off = f*128 + kb*64 + kg*16;
                off ^= (f & 7) << 4;
                bfr[nf] = *(const bf16x8*)((const char*)whs + off);
            }
#pragma unroll
            for (int mi = 0; mi < 2; ++mi)
#pragma unroll
                for (int nf = 0; nf < 4; ++nf)
                    acc[mi][nf] = __builtin_amdgcn_mfma_f32_16x16x32_bf16(
                        af[mi], bfr[nf], acc[mi][nf], 0, 0, 0);
        }
        __syncthreads();
    }
    // --- epilogue: normalize, ELU, store fp32 ---
#pragma unroll
    for (int mi = 0; mi < 2; ++mi)
#pragma unroll
        for (int rg = 0; rg < 4; ++rg) {
            int i = mi*16 + kg*4 + rg;
            float rl = 1.f / l_s[i];
#pragma unroll
            for (int nf = 0; nf < 4; ++nf) {
                float v = acc[mi][nf][rg] * rl;
                v = v > 0.f ? v : expm1f(v);
                out[(size_t)(b*1600 + i0 + i)*256 + w*64 + nf*16 + cl] = v;
            }
        }
}

extern "C" void kernel_launch(void* const* d_in, const int* in_sizes, int n_in,
                              void* d_out, int out_size, void* d_ws, size_t ws_size,
                              hipStream_t stream)
{
    const float* h  = (const float*)d_in[0];
    const int* adj  = (const int*)d_in[1];
    const float* W  = (const float*)d_in[2];
    const float* bW = (const float*)d_in[3];
    const float* ai = (const float*)d_in[4];
    const float* bi = (const float*)d_in[5];
    const float* aj = (const float*)d_in[6];
    const float* bj = (const float*)d_in[7];
    float* out = (float*)d_out;

    char* ws = (char*)d_ws;
    float* Wh = (float*)ws;                                    // 13,107,200 B
    unsigned short* WhT = (unsigned short*)(ws + 13107200);    //  6,553,600 B
    float* Wh1 = (float*)(ws + 13107200 + 6553600);            //     51,200 B
    float* Wh2 = Wh1 + 12800;                                  //     51,200 B

    k_gemm_wh<<<dim3(100, 2), 256, 0, stream>>>(h, W, bW, Wh);
    k_rowdots<<<3200, 256, 0, stream>>>(Wh, ai, bi, aj, bj, Wh1, Wh2);
    k_transpose<<<dim3(25, 4, 8), 256, 0, stream>>>(Wh, WhT);
    k_attn<<<dim3(50, 8), 256, 0, stream>>>(WhT, Wh1, Wh2, adj, out);
}